// Round 12
// baseline (283.549 us; speedup 1.0000x reference)
//
#include <hip/hip_runtime.h>
#include <math.h>

#define D 128
#define MAXD 8
#define EPSV 1e-5f

#define NODES 32          // nodes per block (2 graphs)
#define NI 2              // NODES/16

typedef __attribute__((ext_vector_type(8))) short short8;
typedef __attribute__((ext_vector_type(4))) float f32x4;
typedef __attribute__((ext_vector_type(4))) int i32x4;
typedef unsigned short ushort_t;

// LDS arena (phase-aliased), 32-node tile (~36 KB -> 4 blocks/CU):
//   [0, 8192)       : x (phases A-B), then H (phases C-D)   bf16 swizzled
//   [8192, 25088)   : XGT rz plane [c:128][132B]  (B-C); F tile (D+)
//   [25088, 33792)  : XGT n plane  [c:128][68B]   (B-C); x2 re-stage (D)
#define XH_OFF     0
#define RZ_OFF     8192
#define RZ_STRIDE  132
#define NP_OFF     25088
#define NP_STRIDE  68
#define X2_OFF     NP_OFF
#define F_OFF      RZ_OFF
#define SBIG_BYTES 33792

__device__ __forceinline__ float fast_rcp(float x) { return __builtin_amdgcn_rcpf(x); }
__device__ __forceinline__ float sigmoid_f(float x) {
    return fast_rcp(1.0f + __expf(-x));
}
__device__ __forceinline__ float tanh_f(float x) {
    return 1.0f - 2.0f * fast_rcp(1.0f + __expf(2.0f * x));
}
__device__ __forceinline__ ushort_t f2bf(float f) {
    unsigned int b = __float_as_uint(f);
    b += 0x7FFFu + ((b >> 16) & 1u);
    return (ushort_t)(b >> 16);
}
__device__ __forceinline__ float bf2f(ushort_t u) {
    return __uint_as_float(((unsigned int)u) << 16);
}
// packed bf16 convert: lo = bf16(a), hi = bf16(b), RNE (1 instr vs ~8-10)
__device__ __forceinline__ unsigned int cvt_pk_bf16(float a, float b) {
    unsigned int r;
    asm("v_cvt_pk_bf16_f32 %0, %1, %2" : "=v"(r) : "v"(a), "v"(b));
    return r;
}

// ---------------- prep: bf16 weight images + bn1 affine -------------------
__global__ void prep_kernel(const float* __restrict__ wih, const float* __restrict__ whh,
                            const float* __restrict__ fs,  const float* __restrict__ fn,
                            const float* __restrict__ fu,  const float* __restrict__ fv,
                            const float* __restrict__ fi,
                            const float* __restrict__ g1, const float* __restrict__ b1,
                            const float* __restrict__ m1, const float* __restrict__ v1,
                            ushort_t* __restrict__ wih_bf, ushort_t* __restrict__ whh_bf,
                            ushort_t* __restrict__ fcs_bf, ushort_t* __restrict__ fcn_bf,
                            ushort_t* __restrict__ fcu_bf, ushort_t* __restrict__ fcv_bf,
                            ushort_t* __restrict__ fci_bf,
                            float* __restrict__ bn1sc, float* __restrict__ bn1sh) {
    int i = blockIdx.x * blockDim.x + threadIdx.x;
    if (i < 3 * D * D) {
        wih_bf[i] = f2bf(wih[i]);
        whh_bf[i] = f2bf(whh[i]);
    }
    if (i < D * D) {
        fcs_bf[i] = f2bf(fs[i]);
        fcn_bf[i] = f2bf(fn[i]);
        fcu_bf[i] = f2bf(fu[i]);
        fcv_bf[i] = f2bf(fv[i]);
        fci_bf[i] = f2bf(fi[i]);
    }
    if (i < D) {
        float sc = g1[i] * rsqrtf(v1[i] + EPSV);
        bn1sc[i] = sc;
        bn1sh[i] = b1[i] - m1[i] * sc;
    }
}

// ---------------- mailbox src table --------------------------------------
__global__ void mbinit_kernel(int* __restrict__ mb, int n) {
    int i = blockIdx.x * blockDim.x + threadIdx.x;
    if (i < n) mb[i] = -1;
}
__global__ void scatter_kernel(const int* __restrict__ src, const int* __restrict__ dst,
                               const int* __restrict__ slot, int* __restrict__ mb, int E) {
    int e = blockIdx.x * blockDim.x + threadIdx.x;
    if (e < E) mb[(size_t)dst[e] * MAXD + slot[e]] = src[e];
}

// BN1 staging: 32 rows of feat -> bf16 swizzled tile at dst (512 threads)
__device__ __forceinline__ void stage_bn1(const float* __restrict__ feat,
                                          const float* __restrict__ bn1sc,
                                          const float* __restrict__ bn1sh,
                                          int node0, int tid, char* dst) {
    int row = tid >> 4, u = tid & 15;    // 512 = 32 rows * 16 units
    const float4* fp = (const float4*)(feat + (size_t)(node0 + row) * D + u * 8);
    const float4* scp = (const float4*)(bn1sc + u * 8);
    const float4* shp = (const float4*)(bn1sh + u * 8);
    float4 f0 = fp[0], f1 = fp[1];
    float4 s0 = scp[0], s1 = scp[1];
    float4 h0 = shp[0], h1 = shp[1];
    unsigned int w0 = cvt_pk_bf16(f0.x * s0.x + h0.x, f0.y * s0.y + h0.y);
    unsigned int w1 = cvt_pk_bf16(f0.z * s0.z + h0.z, f0.w * s0.w + h0.w);
    unsigned int w2 = cvt_pk_bf16(f1.x * s1.x + h1.x, f1.y * s1.y + h1.y);
    unsigned int w3 = cvt_pk_bf16(f1.z * s1.z + h1.z, f1.w * s1.w + h1.w);
    *(uint4*)(dst + row * 256 + ((u ^ (row & 7)) << 4)) = make_uint4(w0, w1, w2, w3);
}

// ---------------- mega: BN1+XG+GRU+rst+BN2+attention+readout --------------
// 32 nodes (2 graphs) per block, 512 threads = 8 waves; wave w owns cols
// w*16..w*16+15. Round-12 = round-10 structure (the 64-VGPR / 4-blocks/CU
// optimum; r11's ping-pong cost 20 VGPR -> 3 blocks -> regression) + VALU
// op-count cuts: v_cvt_pk_bf16_f32 for all paired f32->bf16 (staging, XG,
// H, F, intend), i32x4 src-table reads, batched gather loads.
// __launch_bounds__(512, 8) pins the 64-reg/8-wave-per-SIMD budget.
__global__ __launch_bounds__(512, 8) void mega_kernel(
        const float* __restrict__ feat, const int* __restrict__ mb,
        const ushort_t* __restrict__ wih_bf, const ushort_t* __restrict__ whh_bf,
        const float* __restrict__ gbih, const float* __restrict__ gbhh,
        const ushort_t* __restrict__ fcs_bf, const ushort_t* __restrict__ fcn_bf,
        const float* __restrict__ prelu,
        const float* __restrict__ bg, const float* __restrict__ bb,
        const float* __restrict__ bm, const float* __restrict__ bv,
        const ushort_t* __restrict__ fcu_bf, const ushort_t* __restrict__ fcv_bf,
        const ushort_t* __restrict__ fci_bf,
        const float* __restrict__ fvbias, const float* __restrict__ fibias,
        const float* __restrict__ fce,
        const float* __restrict__ intend, const float* __restrict__ pw,
        const float* __restrict__ bn1sc, const float* __restrict__ bn1sh,
        float* __restrict__ outp, int Bn) {
    __shared__ __align__(16) char sBig[SBIG_BYTES];
    __shared__ __align__(16) int sSrcT[MAXD][36];  // [slot][row], block-relative
    __shared__ float sE[NODES][9];
    __shared__ float sAlpha[NODES];
    __shared__ float sPw[NODES];
    __shared__ int   sTmax;

    const int tid = threadIdx.x;
    const int w = tid >> 6;
    const int lane = tid & 63;
    const int lc = lane & 15;
    const int lg = lane >> 4;
    const int c = w * 16 + lc;
    const int node0 = blockIdx.x * NODES;
    const int g0 = blockIdx.x * (NODES / 16);

    const int swzc = c >> 3;
    const int clo = (c & 7) * 2;

    // ---- phase A: stage x = BN1(feat) + src table ----
    if (tid == 0) sTmax = 0;
    stage_bn1(feat, bn1sc, bn1sh, node0, tid, sBig + XH_OFF);
    if (tid < NODES * MAXD) {                   // 256 entries
        int rr = tid >> 3, ss = tid & 7;
        int s = mb[(size_t)(node0 + rr) * MAXD + ss];
        sSrcT[ss][rr] = (s >= 0) ? (s - node0) : -1;
    }
    if (tid < NODES) sPw[tid] = pw[node0 + tid];
    __syncthreads();
    if (tid < NODES) {
        int d = 0;
#pragma unroll
        for (int t = 0; t < MAXD; ++t)
            if (sSrcT[t][tid] >= 0) d = t + 1;
        atomicMax(&sTmax, d);
    }

    // ---- phase B: XG = x @ w_ih^T + b_ih -> transposed LDS planes ----
    {
        short8 bIW[3][4];
#pragma unroll
        for (int g = 0; g < 3; ++g)
#pragma unroll
            for (int kf = 0; kf < 4; ++kf)
                bIW[g][kf] = *(const short8*)(wih_bf + (size_t)(g * D + c) * D + kf * 32 + lg * 8);
        const float bi0 = gbih[c], bi1 = gbih[D + c], bi2 = gbih[2 * D + c];

#pragma unroll
        for (int i = 0; i < NI; ++i) {
            int xrow = i * 16 + lc;
            short8 aF[4];
#pragma unroll
            for (int kf = 0; kf < 4; ++kf)
                aF[kf] = *(const short8*)(sBig + XH_OFF + xrow * 256 + (((kf * 4 + lg) ^ (xrow & 7)) << 4));
            f32x4 aR = {0.f, 0.f, 0.f, 0.f}, aZ = aR, aN = aR;
#pragma unroll
            for (int kf = 0; kf < 4; ++kf) {
                aR = __builtin_amdgcn_mfma_f32_16x16x32_bf16(aF[kf], bIW[0][kf], aR, 0, 0, 0);
                aZ = __builtin_amdgcn_mfma_f32_16x16x32_bf16(aF[kf], bIW[1][kf], aZ, 0, 0, 0);
                aN = __builtin_amdgcn_mfma_f32_16x16x32_bf16(aF[kf], bIW[2][kf], aN, 0, 0, 0);
            }
            // paired packed writes (rows p,p+1 are adjacent in both planes)
            const int row0 = i * 16 + lg * 4;
            unsigned int rz0 = cvt_pk_bf16(aR[0] + bi0, aZ[0] + bi1);
            unsigned int rz1 = cvt_pk_bf16(aR[1] + bi0, aZ[1] + bi1);
            unsigned int rz2 = cvt_pk_bf16(aR[2] + bi0, aZ[2] + bi1);
            unsigned int rz3 = cvt_pk_bf16(aR[3] + bi0, aZ[3] + bi1);
            *(uint2*)(sBig + RZ_OFF + c * RZ_STRIDE + row0 * 4)     = make_uint2(rz0, rz1);
            *(uint2*)(sBig + RZ_OFF + c * RZ_STRIDE + row0 * 4 + 8) = make_uint2(rz2, rz3);
            *(unsigned int*)(sBig + NP_OFF + c * NP_STRIDE + row0 * 2)     = cvt_pk_bf16(aN[0] + bi2, aN[1] + bi2);
            *(unsigned int*)(sBig + NP_OFF + c * NP_STRIDE + row0 * 2 + 4) = cvt_pk_bf16(aN[2] + bi2, aN[3] + bi2);
            __builtin_amdgcn_sched_barrier(0);
        }
    }
    __syncthreads();   // XGT visible; x reads done (step 0 overwrites XH); sTmax final

    // ---- phase C: GRU t-loop (H lives in sBig[XH] as bf16) ----
    const int Tmax = (sTmax > 0) ? sTmax : 1;
    short8 bHW[3][4];
#pragma unroll
    for (int g = 0; g < 3; ++g)
#pragma unroll
        for (int kf = 0; kf < 4; ++kf)
            bHW[g][kf] = *(const short8*)(whh_bf + (size_t)(g * D + c) * D + kf * 32 + lg * 8);
    const float bhr = gbhh[c], bhz = gbhh[D + c], bhn = gbhh[2 * D + c];

    for (int t = 0; t < Tmax; ++t) {
        unsigned int houts[NI][2];
#pragma unroll
        for (int i = 0; i < NI; ++i) {
            f32x4 aR = {0.f, 0.f, 0.f, 0.f}, aZ = aR, aHN = aR;
            if (t != 0) {
                int hrow = i * 16 + lc;
                short8 aF[4];
#pragma unroll
                for (int kf = 0; kf < 4; ++kf)
                    aF[kf] = *(const short8*)(sBig + XH_OFF + hrow * 256 + (((kf * 4 + lg) ^ (hrow & 7)) << 4));
#pragma unroll
                for (int kf = 0; kf < 4; ++kf) {
                    aR  = __builtin_amdgcn_mfma_f32_16x16x32_bf16(aF[kf], bHW[0][kf], aR, 0, 0, 0);
                    aZ  = __builtin_amdgcn_mfma_f32_16x16x32_bf16(aF[kf], bHW[1][kf], aZ, 0, 0, 0);
                    aHN = __builtin_amdgcn_mfma_f32_16x16x32_bf16(aF[kf], bHW[2][kf], aHN, 0, 0, 0);
                }
            }
            // vector src read + batched gathers (LDS latency overlapped)
            i32x4 mvec = *(const i32x4*)&sSrcT[t][i * 16 + lg * 4];
            unsigned int rzv[4];
            ushort_t npv[4];
            int actv[4];
#pragma unroll
            for (int p = 0; p < 4; ++p) {
                int srow = mvec[p];
                actv[p] = srow >= 0;
                int gr = actv[p] ? srow : 0;
                rzv[p] = *(const unsigned int*)(sBig + RZ_OFF + c * RZ_STRIDE + gr * 4);
                npv[p] = *(const ushort_t*)(sBig + NP_OFF + c * NP_STRIDE + gr * 2);
            }
            float holdv[4];
            if (t != 0) {
#pragma unroll
                for (int p = 0; p < 4; ++p) {
                    int row = i * 16 + lg * 4 + p;
                    holdv[p] = bf2f(*(const ushort_t*)(sBig + XH_OFF + row * 256 + ((swzc ^ (row & 7)) << 4) + clo));
                }
            } else {
#pragma unroll
                for (int p = 0; p < 4; ++p) holdv[p] = 0.0f;
            }
            float hnew[4];
#pragma unroll
            for (int p = 0; p < 4; ++p) {
                float gir = __uint_as_float(rzv[p] << 16);
                float giz = __uint_as_float(rzv[p] & 0xffff0000u);
                float gin = bf2f(npv[p]);
                float r = sigmoid_f(gir + aR[p] + bhr);
                float z = sigmoid_f(giz + aZ[p] + bhz);
                float n = tanh_f(gin + r * (aHN[p] + bhn));
                float hv = (1.0f - z) * n + z * holdv[p];
                hnew[p] = actv[p] ? hv : holdv[p];
            }
            houts[i][0] = cvt_pk_bf16(hnew[0], hnew[1]);
            houts[i][1] = cvt_pk_bf16(hnew[2], hnew[3]);
            __builtin_amdgcn_sched_barrier(0);
        }
        __syncthreads();   // all H/XGT reads for this t done
#pragma unroll
        for (int i = 0; i < NI; ++i)
#pragma unroll
            for (int p = 0; p < 4; ++p) {
                int row = i * 16 + lg * 4 + p;
                ushort_t hb = (ushort_t)((houts[i][p >> 1] >> ((p & 1) * 16)) & 0xffffu);
                *(ushort_t*)(sBig + XH_OFF + row * 256 + ((swzc ^ (row & 7)) << 4) + clo) = hb;
            }
        __syncthreads();   // H visible
    }

    // ---- phase D: re-stage x (into NP alias); rst; PReLU; BN2 -> f (RZ alias)
    stage_bn1(feat, bn1sc, bn1sh, node0, tid, sBig + X2_OFF);
    __syncthreads();
    {
        const float pa = prelu[c];
        const float s2 = bg[c] * rsqrtf(bv[c] + EPSV);
        const float h2 = bb[c] - bm[c] * s2;
        const ushort_t* fcs_c = fcs_bf + (size_t)c * D + lg * 8;
        const ushort_t* fcn_c = fcn_bf + (size_t)c * D + lg * 8;
#pragma unroll
        for (int i = 0; i < NI; ++i) {
            int xrow = i * 16 + lc;
            f32x4 a = {0.f, 0.f, 0.f, 0.f};
            {
                short8 xA[4];
#pragma unroll
                for (int kf = 0; kf < 4; ++kf)
                    xA[kf] = *(const short8*)(sBig + X2_OFF + xrow * 256 + (((kf * 4 + lg) ^ (xrow & 7)) << 4));
#pragma unroll
                for (int kf = 0; kf < 4; ++kf)
                    a = __builtin_amdgcn_mfma_f32_16x16x32_bf16(xA[kf], *(const short8*)(fcs_c + kf * 32), a, 0, 0, 0);
            }
            {
                short8 hA[4];
#pragma unroll
                for (int kf = 0; kf < 4; ++kf)
                    hA[kf] = *(const short8*)(sBig + XH_OFF + xrow * 256 + (((kf * 4 + lg) ^ (xrow & 7)) << 4));
#pragma unroll
                for (int kf = 0; kf < 4; ++kf)
                    a = __builtin_amdgcn_mfma_f32_16x16x32_bf16(hA[kf], *(const short8*)(fcn_c + kf * 32), a, 0, 0, 0);
            }
            float vv[4];
#pragma unroll
            for (int p = 0; p < 4; ++p) {
                float v = a[p];
                v = v > 0.0f ? v : pa * v;
                vv[p] = v * s2 + h2;
            }
            unsigned int pk01 = cvt_pk_bf16(vv[0], vv[1]);
            unsigned int pk23 = cvt_pk_bf16(vv[2], vv[3]);
#pragma unroll
            for (int p = 0; p < 4; ++p) {
                int row = i * 16 + lg * 4 + p;
                ushort_t fb = (ushort_t)(((p & 1) ? ((p >> 1) ? pk23 : pk01) >> 16
                                                  : ((p >> 1) ? pk23 : pk01)) & 0xffffu);
                *(ushort_t*)(sBig + F_OFF + row * 256 + ((swzc ^ (row & 7)) << 4) + clo) = fb;
            }
            __builtin_amdgcn_sched_barrier(0);
        }
    }
    __syncthreads();   // f visible

    // ---- phase E: attention scores ----
    {
        const ushort_t* fcu_c = fcu_bf + (size_t)c * D + lg * 8;
        const ushort_t* fcv_c = fcv_bf + (size_t)c * D + lg * 8;
        const ushort_t* fci_c = fci_bf + (size_t)c * D + lg * 8;
        f32x4 vl4 = {0.f, 0.f, 0.f, 0.f};
        {
            int vrow = g0 + (lc & 1);       // 2 graphs; other rows duplicate
#pragma unroll
            for (int kf = 0; kf < 4; ++kf) {
                const float* ip = intend + (size_t)vrow * D + kf * 32 + lg * 8;
                float4 a0 = ((const float4*)ip)[0], a1 = ((const float4*)ip)[1];
                union { short8 v; unsigned int u[4]; } av;
                av.u[0] = cvt_pk_bf16(a0.x, a0.y);
                av.u[1] = cvt_pk_bf16(a0.z, a0.w);
                av.u[2] = cvt_pk_bf16(a1.x, a1.y);
                av.u[3] = cvt_pk_bf16(a1.z, a1.w);
                vl4 = __builtin_amdgcn_mfma_f32_16x16x32_bf16(av.v, *(const short8*)(fcv_c + kf * 32), vl4, 0, 0, 0);
            }
            int lrow = (lc & 1) * 16 + 15;  // last node of graph lc&1
#pragma unroll
            for (int kf = 0; kf < 4; ++kf) {
                short8 al = *(const short8*)(sBig + F_OFF + lrow * 256 + (((kf * 4 + lg) ^ (lrow & 7)) << 4));
                vl4 = __builtin_amdgcn_mfma_f32_16x16x32_bf16(al, *(const short8*)(fci_c + kf * 32), vl4, 0, 0, 0);
            }
        }
        const float vbias = fvbias[c] + fibias[c];
        float vl_b[4];
#pragma unroll
        for (int p = 0; p < 4; ++p) vl_b[p] = vl4[p] + vbias;
        const float fcec = fce[c];

#pragma unroll
        for (int i = 0; i < NI; ++i) {
            int frow = i * 16 + lc;
            f32x4 u4 = {0.f, 0.f, 0.f, 0.f};
#pragma unroll
            for (int kf = 0; kf < 4; ++kf) {
                short8 af = *(const short8*)(sBig + F_OFF + frow * 256 + (((kf * 4 + lg) ^ (frow & 7)) << 4));
                u4 = __builtin_amdgcn_mfma_f32_16x16x32_bf16(af, *(const short8*)(fcu_c + kf * 32), u4, 0, 0, 0);
            }
            // vl[graph i][col c] is held by lane (lg'=0, lc'=lc), slot p'=i
            float vli = __shfl(vl_b[i & 3], lc, 64);
#pragma unroll
            for (int p = 0; p < 4; ++p) {
                float ev = sigmoid_f(u4[p] + vli) * fcec;
                ev += __shfl_xor(ev, 1);
                ev += __shfl_xor(ev, 2);
                ev += __shfl_xor(ev, 4);
                ev += __shfl_xor(ev, 8);
                if (lc == 0) sE[i * 16 + lg * 4 + p][w] = ev;
            }
            __builtin_amdgcn_sched_barrier(0);
        }
    }
    __syncthreads();

    // ---- phase E2: per-graph softmax over 16 nodes ----
    if (tid < NODES) {
        float e = 0.0f;
#pragma unroll
        for (int q = 0; q < 8; ++q) e += sE[tid][q];
        float mx = e;
        mx = fmaxf(mx, __shfl_xor(mx, 1));
        mx = fmaxf(mx, __shfl_xor(mx, 2));
        mx = fmaxf(mx, __shfl_xor(mx, 4));
        mx = fmaxf(mx, __shfl_xor(mx, 8));
        float ex = __expf(e - mx);
        float sm = ex;
        sm += __shfl_xor(sm, 1);
        sm += __shfl_xor(sm, 2);
        sm += __shfl_xor(sm, 4);
        sm += __shfl_xor(sm, 8);
        sAlpha[tid] = ex * fast_rcp(sm);
    }
    __syncthreads();

    // ---- phase F: readouts (f read back from LDS) ----
#pragma unroll
    for (int i = 0; i < NI; ++i) {
        float ra = 0.0f, pb = 0.0f;
#pragma unroll
        for (int p = 0; p < 4; ++p) {
            int row = i * 16 + lg * 4 + p;
            float fv = bf2f(*(const ushort_t*)(sBig + F_OFF + row * 256 + ((swzc ^ (row & 7)) << 4) + clo));
            ra = fmaf(sAlpha[row], fv, ra);
            pb = fmaf(sPw[row],    fv, pb);
        }
        ra += __shfl_xor(ra, 16);
        ra += __shfl_xor(ra, 32);
        pb += __shfl_xor(pb, 16);
        pb += __shfl_xor(pb, 32);
        if (lg == 0) {
            outp[(size_t)(g0 + i) * D + c] = ra;
            outp[(size_t)Bn * D + (size_t)(g0 + i) * D + c] = pb;
        }
    }
}

// -------------------------------------------------------------------------
extern "C" void kernel_launch(void* const* d_in, const int* in_sizes, int n_in,
                              void* d_out, int out_size, void* d_ws, size_t ws_size,
                              hipStream_t stream) {
    const float* feat   = (const float*)d_in[0];
    const float* intend = (const float*)d_in[1];
    const float* posw   = (const float*)d_in[2];
    const float* bn1g   = (const float*)d_in[3];
    const float* bn1b   = (const float*)d_in[4];
    const float* bn1m   = (const float*)d_in[5];
    const float* bn1v   = (const float*)d_in[6];
    const float* gwih   = (const float*)d_in[7];
    const float* gwhh   = (const float*)d_in[8];
    const float* gbih   = (const float*)d_in[9];
    const float* gbhh   = (const float*)d_in[10];
    const float* fcs    = (const float*)d_in[11];
    const float* fcn    = (const float*)d_in[12];
    const float* prelu  = (const float*)d_in[13];
    const float* bn2g   = (const float*)d_in[14];
    const float* bn2b   = (const float*)d_in[15];
    const float* bn2m   = (const float*)d_in[16];
    const float* bn2v   = (const float*)d_in[17];
    const float* fcu    = (const float*)d_in[18];
    const float* fcv    = (const float*)d_in[19];
    const float* fcvb   = (const float*)d_in[20];
    const float* fci    = (const float*)d_in[21];
    const float* fcib   = (const float*)d_in[22];
    const float* fce    = (const float*)d_in[23];
    const int* esrc     = (const int*)d_in[25];
    const int* edst     = (const int*)d_in[26];
    const int* eslot    = (const int*)d_in[27];

    const int N = in_sizes[0] / D;
    const int B = in_sizes[1] / D;
    const int E = in_sizes[25];

    char* wsb = (char*)d_ws;
    ushort_t* wih_bf = (ushort_t*)wsb;                 // 3*D*D
    ushort_t* whh_bf = wih_bf + 3 * D * D;
    ushort_t* fcs_bf = whh_bf + 3 * D * D;             // D*D each
    ushort_t* fcn_bf = fcs_bf + D * D;
    ushort_t* fcu_bf = fcn_bf + D * D;
    ushort_t* fcv_bf = fcu_bf + D * D;
    ushort_t* fci_bf = fcv_bf + D * D;
    float* bn1sc = (float*)(fci_bf + D * D);
    float* bn1sh = bn1sc + D;
    int*   mb    = (int*)(bn1sh + D);                  // N*MAXD

    prep_kernel<<<(3 * D * D + 255) / 256, 256, 0, stream>>>(
        gwih, gwhh, fcs, fcn, fcu, fcv, fci,
        bn1g, bn1b, bn1m, bn1v,
        wih_bf, whh_bf, fcs_bf, fcn_bf, fcu_bf, fcv_bf, fci_bf, bn1sc, bn1sh);
    mbinit_kernel<<<(N * MAXD + 255) / 256, 256, 0, stream>>>(mb, N * MAXD);
    scatter_kernel<<<(E + 255) / 256, 256, 0, stream>>>(esrc, edst, eslot, mb, E);
    mega_kernel<<<N / NODES, 512, 0, stream>>>(
        feat, mb, wih_bf, whh_bf, gbih, gbhh, fcs_bf, fcn_bf,
        prelu, bn2g, bn2b, bn2m, bn2v,
        fcu_bf, fcv_bf, fci_bf, fcvb, fcib, fce,
        intend, posw, bn1sc, bn1sh, (float*)d_out, B);
}

// Round 13
// 134.257 us; speedup vs baseline: 2.1120x; 2.1120x over previous
//
#include <hip/hip_runtime.h>
#include <math.h>

#define D 128
#define MAXD 8
#define EPSV 1e-5f

#define NODES 32          // nodes per block (2 graphs)
#define NI 2              // NODES/16

typedef __attribute__((ext_vector_type(8))) short short8;
typedef __attribute__((ext_vector_type(4))) float f32x4;
typedef unsigned short ushort_t;

// LDS arena (phase-aliased), 32-node tile (~36 KB -> 4 blocks/CU):
//   [0, 8192)       : x (phases A-B), then H (phases C-D)   bf16 swizzled
//   [8192, 25088)   : XGT rz plane [c:128][132B]  (B-C); F tile (D+)
//   [25088, 33792)  : XGT n plane  [c:128][68B]   (B-C); x2 re-stage (D)
#define XH_OFF     0
#define RZ_OFF     8192
#define RZ_STRIDE  132
#define NP_OFF     25088
#define NP_STRIDE  68
#define X2_OFF     NP_OFF
#define F_OFF      RZ_OFF
#define SBIG_BYTES 33792

__device__ __forceinline__ float fast_rcp(float x) { return __builtin_amdgcn_rcpf(x); }
__device__ __forceinline__ float sigmoid_f(float x) {
    return fast_rcp(1.0f + __expf(-x));
}
__device__ __forceinline__ float tanh_f(float x) {
    return 1.0f - 2.0f * fast_rcp(1.0f + __expf(2.0f * x));
}
__device__ __forceinline__ ushort_t f2bf(float f) {
    unsigned int b = __float_as_uint(f);
    b += 0x7FFFu + ((b >> 16) & 1u);
    return (ushort_t)(b >> 16);
}
__device__ __forceinline__ float bf2f(ushort_t u) {
    return __uint_as_float(((unsigned int)u) << 16);
}
// packed bf16 convert: lo = bf16(a), hi = bf16(b), RNE (1 instr vs ~8-10)
__device__ __forceinline__ unsigned int cvt_pk_bf16(float a, float b) {
    unsigned int r;
    asm("v_cvt_pk_bf16_f32 %0, %1, %2" : "=v"(r) : "v"(a), "v"(b));
    return r;
}

// ---------------- prep: bf16 weight images + bn1 affine -------------------
__global__ void prep_kernel(const float* __restrict__ wih, const float* __restrict__ whh,
                            const float* __restrict__ fs,  const float* __restrict__ fn,
                            const float* __restrict__ fu,  const float* __restrict__ fv,
                            const float* __restrict__ fi,
                            const float* __restrict__ g1, const float* __restrict__ b1,
                            const float* __restrict__ m1, const float* __restrict__ v1,
                            ushort_t* __restrict__ wih_bf, ushort_t* __restrict__ whh_bf,
                            ushort_t* __restrict__ fcs_bf, ushort_t* __restrict__ fcn_bf,
                            ushort_t* __restrict__ fcu_bf, ushort_t* __restrict__ fcv_bf,
                            ushort_t* __restrict__ fci_bf,
                            float* __restrict__ bn1sc, float* __restrict__ bn1sh) {
    int i = blockIdx.x * blockDim.x + threadIdx.x;
    if (i < 3 * D * D) {
        wih_bf[i] = f2bf(wih[i]);
        whh_bf[i] = f2bf(whh[i]);
    }
    if (i < D * D) {
        fcs_bf[i] = f2bf(fs[i]);
        fcn_bf[i] = f2bf(fn[i]);
        fcu_bf[i] = f2bf(fu[i]);
        fcv_bf[i] = f2bf(fv[i]);
        fci_bf[i] = f2bf(fi[i]);
    }
    if (i < D) {
        float sc = g1[i] * rsqrtf(v1[i] + EPSV);
        bn1sc[i] = sc;
        bn1sh[i] = b1[i] - m1[i] * sc;
    }
}

// ---------------- mailbox src table --------------------------------------
__global__ void mbinit_kernel(int* __restrict__ mb, int n) {
    int i = blockIdx.x * blockDim.x + threadIdx.x;
    if (i < n) mb[i] = -1;
}
__global__ void scatter_kernel(const int* __restrict__ src, const int* __restrict__ dst,
                               const int* __restrict__ slot, int* __restrict__ mb, int E) {
    int e = blockIdx.x * blockDim.x + threadIdx.x;
    if (e < E) mb[(size_t)dst[e] * MAXD + slot[e]] = src[e];
}

// BN1 staging: 32 rows of feat -> bf16 swizzled tile at dst (512 threads)
__device__ __forceinline__ void stage_bn1(const float* __restrict__ feat,
                                          const float* __restrict__ bn1sc,
                                          const float* __restrict__ bn1sh,
                                          int node0, int tid, char* dst) {
    int row = tid >> 4, u = tid & 15;    // 512 = 32 rows * 16 units
    const float4* fp = (const float4*)(feat + (size_t)(node0 + row) * D + u * 8);
    const float4* scp = (const float4*)(bn1sc + u * 8);
    const float4* shp = (const float4*)(bn1sh + u * 8);
    float4 f0 = fp[0], f1 = fp[1];
    float4 s0 = scp[0], s1 = scp[1];
    float4 h0 = shp[0], h1 = shp[1];
    unsigned int w0 = cvt_pk_bf16(f0.x * s0.x + h0.x, f0.y * s0.y + h0.y);
    unsigned int w1 = cvt_pk_bf16(f0.z * s0.z + h0.z, f0.w * s0.w + h0.w);
    unsigned int w2 = cvt_pk_bf16(f1.x * s1.x + h1.x, f1.y * s1.y + h1.y);
    unsigned int w3 = cvt_pk_bf16(f1.z * s1.z + h1.z, f1.w * s1.w + h1.w);
    *(uint4*)(dst + row * 256 + ((u ^ (row & 7)) << 4)) = make_uint4(w0, w1, w2, w3);
}

// ---------------- mega: BN1+XG+GRU+rst+BN2+attention+readout --------------
// 32 nodes (2 graphs) per block, 512 threads = 8 waves; wave w owns cols
// w*16..w*16+15. Round-13 = round-10 structure (64-VGPR / 4-blocks/CU
// optimum) + v_cvt_pk_bf16_f32 for paired f32->bf16 packs only.
// LAUNCH BOUNDS LAW (r3-r12 evidence): (512,2) -> 64-80 VGPR, no spill;
// (512,1)/waves_per_eu(2,2) -> 128 cap w/ spill; (512,8) -> 32 cap w/
// catastrophic spill (r12: 1.07 GB/launch). DO NOT change from (512,2).
__global__ __launch_bounds__(512, 2) void mega_kernel(
        const float* __restrict__ feat, const int* __restrict__ mb,
        const ushort_t* __restrict__ wih_bf, const ushort_t* __restrict__ whh_bf,
        const float* __restrict__ gbih, const float* __restrict__ gbhh,
        const ushort_t* __restrict__ fcs_bf, const ushort_t* __restrict__ fcn_bf,
        const float* __restrict__ prelu,
        const float* __restrict__ bg, const float* __restrict__ bb,
        const float* __restrict__ bm, const float* __restrict__ bv,
        const ushort_t* __restrict__ fcu_bf, const ushort_t* __restrict__ fcv_bf,
        const ushort_t* __restrict__ fci_bf,
        const float* __restrict__ fvbias, const float* __restrict__ fibias,
        const float* __restrict__ fce,
        const float* __restrict__ intend, const float* __restrict__ pw,
        const float* __restrict__ bn1sc, const float* __restrict__ bn1sh,
        float* __restrict__ outp, int Bn) {
    __shared__ __align__(16) char sBig[SBIG_BYTES];
    __shared__ __align__(16) int sSrcT[MAXD][36];  // [slot][row], block-relative
    __shared__ float sE[NODES][9];
    __shared__ float sAlpha[NODES];
    __shared__ float sPw[NODES];
    __shared__ int   sTmax;

    const int tid = threadIdx.x;
    const int w = tid >> 6;
    const int lane = tid & 63;
    const int lc = lane & 15;
    const int lg = lane >> 4;
    const int c = w * 16 + lc;
    const int node0 = blockIdx.x * NODES;
    const int g0 = blockIdx.x * (NODES / 16);

    const int swzc = c >> 3;
    const int clo = (c & 7) * 2;

    // ---- phase A: stage x = BN1(feat) + src table ----
    if (tid == 0) sTmax = 0;
    stage_bn1(feat, bn1sc, bn1sh, node0, tid, sBig + XH_OFF);
    if (tid < NODES * MAXD) {                   // 256 entries
        int rr = tid >> 3, ss = tid & 7;
        int s = mb[(size_t)(node0 + rr) * MAXD + ss];
        sSrcT[ss][rr] = (s >= 0) ? (s - node0) : -1;
    }
    if (tid < NODES) sPw[tid] = pw[node0 + tid];
    __syncthreads();
    if (tid < NODES) {
        int d = 0;
#pragma unroll
        for (int t = 0; t < MAXD; ++t)
            if (sSrcT[t][tid] >= 0) d = t + 1;
        atomicMax(&sTmax, d);
    }

    // ---- phase B: XG = x @ w_ih^T + b_ih -> transposed LDS planes ----
    {
        short8 bIW[3][4];
#pragma unroll
        for (int g = 0; g < 3; ++g)
#pragma unroll
            for (int kf = 0; kf < 4; ++kf)
                bIW[g][kf] = *(const short8*)(wih_bf + (size_t)(g * D + c) * D + kf * 32 + lg * 8);
        const float bi0 = gbih[c], bi1 = gbih[D + c], bi2 = gbih[2 * D + c];

#pragma unroll
        for (int i = 0; i < NI; ++i) {
            int xrow = i * 16 + lc;
            short8 aF[4];
#pragma unroll
            for (int kf = 0; kf < 4; ++kf)
                aF[kf] = *(const short8*)(sBig + XH_OFF + xrow * 256 + (((kf * 4 + lg) ^ (xrow & 7)) << 4));
            f32x4 aR = {0.f, 0.f, 0.f, 0.f}, aZ = aR, aN = aR;
#pragma unroll
            for (int kf = 0; kf < 4; ++kf) {
                aR = __builtin_amdgcn_mfma_f32_16x16x32_bf16(aF[kf], bIW[0][kf], aR, 0, 0, 0);
                aZ = __builtin_amdgcn_mfma_f32_16x16x32_bf16(aF[kf], bIW[1][kf], aZ, 0, 0, 0);
                aN = __builtin_amdgcn_mfma_f32_16x16x32_bf16(aF[kf], bIW[2][kf], aN, 0, 0, 0);
            }
            // packed writes; rows p are adjacent: r|z plane holds (r,z) per row
            const int row0 = i * 16 + lg * 4;
            unsigned int rz0 = cvt_pk_bf16(aR[0] + bi0, aZ[0] + bi1);
            unsigned int rz1 = cvt_pk_bf16(aR[1] + bi0, aZ[1] + bi1);
            unsigned int rz2 = cvt_pk_bf16(aR[2] + bi0, aZ[2] + bi1);
            unsigned int rz3 = cvt_pk_bf16(aR[3] + bi0, aZ[3] + bi1);
            *(uint2*)(sBig + RZ_OFF + c * RZ_STRIDE + row0 * 4)     = make_uint2(rz0, rz1);
            *(uint2*)(sBig + RZ_OFF + c * RZ_STRIDE + row0 * 4 + 8) = make_uint2(rz2, rz3);
            *(unsigned int*)(sBig + NP_OFF + c * NP_STRIDE + row0 * 2)     = cvt_pk_bf16(aN[0] + bi2, aN[1] + bi2);
            *(unsigned int*)(sBig + NP_OFF + c * NP_STRIDE + row0 * 2 + 4) = cvt_pk_bf16(aN[2] + bi2, aN[3] + bi2);
            __builtin_amdgcn_sched_barrier(0);
        }
    }
    __syncthreads();   // XGT visible; x reads done (step 0 overwrites XH); sTmax final

    // ---- phase C: GRU t-loop (H lives in sBig[XH] as bf16) ----
    const int Tmax = (sTmax > 0) ? sTmax : 1;
    short8 bHW[3][4];
#pragma unroll
    for (int g = 0; g < 3; ++g)
#pragma unroll
        for (int kf = 0; kf < 4; ++kf)
            bHW[g][kf] = *(const short8*)(whh_bf + (size_t)(g * D + c) * D + kf * 32 + lg * 8);
    const float bhr = gbhh[c], bhz = gbhh[D + c], bhn = gbhh[2 * D + c];

    for (int t = 0; t < Tmax; ++t) {
        unsigned int houts[NI][2];
#pragma unroll
        for (int i = 0; i < NI; ++i) {
            f32x4 aR = {0.f, 0.f, 0.f, 0.f}, aZ = aR, aHN = aR;
            if (t != 0) {
                int hrow = i * 16 + lc;
                short8 aF[4];
#pragma unroll
                for (int kf = 0; kf < 4; ++kf)
                    aF[kf] = *(const short8*)(sBig + XH_OFF + hrow * 256 + (((kf * 4 + lg) ^ (hrow & 7)) << 4));
#pragma unroll
                for (int kf = 0; kf < 4; ++kf) {
                    aR  = __builtin_amdgcn_mfma_f32_16x16x32_bf16(aF[kf], bHW[0][kf], aR, 0, 0, 0);
                    aZ  = __builtin_amdgcn_mfma_f32_16x16x32_bf16(aF[kf], bHW[1][kf], aZ, 0, 0, 0);
                    aHN = __builtin_amdgcn_mfma_f32_16x16x32_bf16(aF[kf], bHW[2][kf], aHN, 0, 0, 0);
                }
            }
            float hnew[4];
#pragma unroll
            for (int p = 0; p < 4; ++p) {
                int row = i * 16 + lg * 4 + p;
                int srow = sSrcT[t][row];
                int act = srow >= 0;
                int gr = act ? srow : 0;
                unsigned int rz = *(const unsigned int*)(sBig + RZ_OFF + c * RZ_STRIDE + gr * 4);
                float gir = __uint_as_float(rz << 16);
                float giz = __uint_as_float(rz & 0xffff0000u);
                float gin = bf2f(*(const ushort_t*)(sBig + NP_OFF + c * NP_STRIDE + gr * 2));
                float hold = 0.0f;
                if (t != 0)
                    hold = bf2f(*(const ushort_t*)(sBig + XH_OFF + row * 256 + ((swzc ^ (row & 7)) << 4) + clo));
                float r = sigmoid_f(gir + aR[p] + bhr);
                float z = sigmoid_f(giz + aZ[p] + bhz);
                float n = tanh_f(gin + r * (aHN[p] + bhn));
                float hv = (1.0f - z) * n + z * hold;
                hnew[p] = act ? hv : hold;
            }
            houts[i][0] = cvt_pk_bf16(hnew[0], hnew[1]);
            houts[i][1] = cvt_pk_bf16(hnew[2], hnew[3]);
            __builtin_amdgcn_sched_barrier(0);
        }
        __syncthreads();   // all H/XGT reads for this t done
#pragma unroll
        for (int i = 0; i < NI; ++i)
#pragma unroll
            for (int p = 0; p < 4; ++p) {
                int row = i * 16 + lg * 4 + p;
                ushort_t hb = (ushort_t)((houts[i][p >> 1] >> ((p & 1) * 16)) & 0xffffu);
                *(ushort_t*)(sBig + XH_OFF + row * 256 + ((swzc ^ (row & 7)) << 4) + clo) = hb;
            }
        __syncthreads();   // H visible
    }

    // ---- phase D: re-stage x (into NP alias); rst; PReLU; BN2 -> f (RZ alias)
    stage_bn1(feat, bn1sc, bn1sh, node0, tid, sBig + X2_OFF);
    __syncthreads();
    {
        const float pa = prelu[c];
        const float s2 = bg[c] * rsqrtf(bv[c] + EPSV);
        const float h2 = bb[c] - bm[c] * s2;
        const ushort_t* fcs_c = fcs_bf + (size_t)c * D + lg * 8;
        const ushort_t* fcn_c = fcn_bf + (size_t)c * D + lg * 8;
#pragma unroll
        for (int i = 0; i < NI; ++i) {
            int xrow = i * 16 + lc;
            f32x4 a = {0.f, 0.f, 0.f, 0.f};
            {
                short8 xA[4];
#pragma unroll
                for (int kf = 0; kf < 4; ++kf)
                    xA[kf] = *(const short8*)(sBig + X2_OFF + xrow * 256 + (((kf * 4 + lg) ^ (xrow & 7)) << 4));
#pragma unroll
                for (int kf = 0; kf < 4; ++kf)
                    a = __builtin_amdgcn_mfma_f32_16x16x32_bf16(xA[kf], *(const short8*)(fcs_c + kf * 32), a, 0, 0, 0);
            }
            {
                short8 hA[4];
#pragma unroll
                for (int kf = 0; kf < 4; ++kf)
                    hA[kf] = *(const short8*)(sBig + XH_OFF + xrow * 256 + (((kf * 4 + lg) ^ (xrow & 7)) << 4));
#pragma unroll
                for (int kf = 0; kf < 4; ++kf)
                    a = __builtin_amdgcn_mfma_f32_16x16x32_bf16(hA[kf], *(const short8*)(fcn_c + kf * 32), a, 0, 0, 0);
            }
#pragma unroll
            for (int p = 0; p < 4; ++p) {
                int row = i * 16 + lg * 4 + p;
                float v = a[p];
                v = v > 0.0f ? v : pa * v;
                v = v * s2 + h2;
                *(ushort_t*)(sBig + F_OFF + row * 256 + ((swzc ^ (row & 7)) << 4) + clo) = f2bf(v);
            }
            __builtin_amdgcn_sched_barrier(0);
        }
    }
    __syncthreads();   // f visible

    // ---- phase E: attention scores ----
    {
        const ushort_t* fcu_c = fcu_bf + (size_t)c * D + lg * 8;
        const ushort_t* fcv_c = fcv_bf + (size_t)c * D + lg * 8;
        const ushort_t* fci_c = fci_bf + (size_t)c * D + lg * 8;
        f32x4 vl4 = {0.f, 0.f, 0.f, 0.f};
        {
            int vrow = g0 + (lc & 1);       // 2 graphs; other rows duplicate
#pragma unroll
            for (int kf = 0; kf < 4; ++kf) {
                const float* ip = intend + (size_t)vrow * D + kf * 32 + lg * 8;
                float4 a0 = ((const float4*)ip)[0], a1 = ((const float4*)ip)[1];
                union { short8 v; unsigned int u[4]; } av;
                av.u[0] = cvt_pk_bf16(a0.x, a0.y);
                av.u[1] = cvt_pk_bf16(a0.z, a0.w);
                av.u[2] = cvt_pk_bf16(a1.x, a1.y);
                av.u[3] = cvt_pk_bf16(a1.z, a1.w);
                vl4 = __builtin_amdgcn_mfma_f32_16x16x32_bf16(av.v, *(const short8*)(fcv_c + kf * 32), vl4, 0, 0, 0);
            }
            int lrow = (lc & 1) * 16 + 15;  // last node of graph lc&1
#pragma unroll
            for (int kf = 0; kf < 4; ++kf) {
                short8 al = *(const short8*)(sBig + F_OFF + lrow * 256 + (((kf * 4 + lg) ^ (lrow & 7)) << 4));
                vl4 = __builtin_amdgcn_mfma_f32_16x16x32_bf16(al, *(const short8*)(fci_c + kf * 32), vl4, 0, 0, 0);
            }
        }
        const float vbias = fvbias[c] + fibias[c];
        float vl_b[4];
#pragma unroll
        for (int p = 0; p < 4; ++p) vl_b[p] = vl4[p] + vbias;
        const float fcec = fce[c];

#pragma unroll
        for (int i = 0; i < NI; ++i) {
            int frow = i * 16 + lc;
            f32x4 u4 = {0.f, 0.f, 0.f, 0.f};
#pragma unroll
            for (int kf = 0; kf < 4; ++kf) {
                short8 af = *(const short8*)(sBig + F_OFF + frow * 256 + (((kf * 4 + lg) ^ (frow & 7)) << 4));
                u4 = __builtin_amdgcn_mfma_f32_16x16x32_bf16(af, *(const short8*)(fcu_c + kf * 32), u4, 0, 0, 0);
            }
            // vl[graph i][col c] is held by lane (lg'=0, lc'=lc), slot p'=i
            float vli = __shfl(vl_b[i & 3], lc, 64);
#pragma unroll
            for (int p = 0; p < 4; ++p) {
                float ev = sigmoid_f(u4[p] + vli) * fcec;
                ev += __shfl_xor(ev, 1);
                ev += __shfl_xor(ev, 2);
                ev += __shfl_xor(ev, 4);
                ev += __shfl_xor(ev, 8);
                if (lc == 0) sE[i * 16 + lg * 4 + p][w] = ev;
            }
            __builtin_amdgcn_sched_barrier(0);
        }
    }
    __syncthreads();

    // ---- phase E2: per-graph softmax over 16 nodes ----
    if (tid < NODES) {
        float e = 0.0f;
#pragma unroll
        for (int q = 0; q < 8; ++q) e += sE[tid][q];
        float mx = e;
        mx = fmaxf(mx, __shfl_xor(mx, 1));
        mx = fmaxf(mx, __shfl_xor(mx, 2));
        mx = fmaxf(mx, __shfl_xor(mx, 4));
        mx = fmaxf(mx, __shfl_xor(mx, 8));
        float ex = __expf(e - mx);
        float sm = ex;
        sm += __shfl_xor(sm, 1);
        sm += __shfl_xor(sm, 2);
        sm += __shfl_xor(sm, 4);
        sm += __shfl_xor(sm, 8);
        sAlpha[tid] = ex * fast_rcp(sm);
    }
    __syncthreads();

    // ---- phase F: readouts (f read back from LDS) ----
#pragma unroll
    for (int i = 0; i < NI; ++i) {
        float ra = 0.0f, pb = 0.0f;
#pragma unroll
        for (int p = 0; p < 4; ++p) {
            int row = i * 16 + lg * 4 + p;
            float fv = bf2f(*(const ushort_t*)(sBig + F_OFF + row * 256 + ((swzc ^ (row & 7)) << 4) + clo));
            ra = fmaf(sAlpha[row], fv, ra);
            pb = fmaf(sPw[row],    fv, pb);
        }
        ra += __shfl_xor(ra, 16);
        ra += __shfl_xor(ra, 32);
        pb += __shfl_xor(pb, 16);
        pb += __shfl_xor(pb, 32);
        if (lg == 0) {
            outp[(size_t)(g0 + i) * D + c] = ra;
            outp[(size_t)Bn * D + (size_t)(g0 + i) * D + c] = pb;
        }
    }
}

// -------------------------------------------------------------------------
extern "C" void kernel_launch(void* const* d_in, const int* in_sizes, int n_in,
                              void* d_out, int out_size, void* d_ws, size_t ws_size,
                              hipStream_t stream) {
    const float* feat   = (const float*)d_in[0];
    const float* intend = (const float*)d_in[1];
    const float* posw   = (const float*)d_in[2];
    const float* bn1g   = (const float*)d_in[3];
    const float* bn1b   = (const float*)d_in[4];
    const float* bn1m   = (const float*)d_in[5];
    const float* bn1v   = (const float*)d_in[6];
    const float* gwih   = (const float*)d_in[7];
    const float* gwhh   = (const float*)d_in[8];
    const float* gbih   = (const float*)d_in[9];
    const float* gbhh   = (const float*)d_in[10];
    const float* fcs    = (const float*)d_in[11];
    const float* fcn    = (const float*)d_in[12];
    const float* prelu  = (const float*)d_in[13];
    const float* bn2g   = (const float*)d_in[14];
    const float* bn2b   = (const float*)d_in[15];
    const float* bn2m   = (const float*)d_in[16];
    const float* bn2v   = (const float*)d_in[17];
    const float* fcu    = (const float*)d_in[18];
    const float* fcv    = (const float*)d_in[19];
    const float* fcvb   = (const float*)d_in[20];
    const float* fci    = (const float*)d_in[21];
    const float* fcib   = (const float*)d_in[22];
    const float* fce    = (const float*)d_in[23];
    const int* esrc     = (const int*)d_in[25];
    const int* edst     = (const int*)d_in[26];
    const int* eslot    = (const int*)d_in[27];

    const int N = in_sizes[0] / D;
    const int B = in_sizes[1] / D;
    const int E = in_sizes[25];

    char* wsb = (char*)d_ws;
    ushort_t* wih_bf = (ushort_t*)wsb;                 // 3*D*D
    ushort_t* whh_bf = wih_bf + 3 * D * D;
    ushort_t* fcs_bf = whh_bf + 3 * D * D;             // D*D each
    ushort_t* fcn_bf = fcs_bf + D * D;
    ushort_t* fcu_bf = fcn_bf + D * D;
    ushort_t* fcv_bf = fcu_bf + D * D;
    ushort_t* fci_bf = fcv_bf + D * D;
    float* bn1sc = (float*)(fci_bf + D * D);
    float* bn1sh = bn1sc + D;
    int*   mb    = (int*)(bn1sh + D);                  // N*MAXD

    prep_kernel<<<(3 * D * D + 255) / 256, 256, 0, stream>>>(
        gwih, gwhh, fcs, fcn, fcu, fcv, fci,
        bn1g, bn1b, bn1m, bn1v,
        wih_bf, whh_bf, fcs_bf, fcn_bf, fcu_bf, fcv_bf, fci_bf, bn1sc, bn1sh);
    mbinit_kernel<<<(N * MAXD + 255) / 256, 256, 0, stream>>>(mb, N * MAXD);
    scatter_kernel<<<(E + 255) / 256, 256, 0, stream>>>(esrc, edst, eslot, mb, E);
    mega_kernel<<<N / NODES, 512, 0, stream>>>(
        feat, mb, wih_bf, whh_bf, gbih, gbhh, fcs_bf, fcn_bf,
        prelu, bn2g, bn2b, bn2m, bn2v,
        fcu_bf, fcv_bf, fci_bf, fcvb, fcib, fce,
        intend, posw, bn1sc, bn1sh, (float*)d_out, B);
}